// Round 1
// 375.910 us; speedup vs baseline: 1.0199x; 1.0199x over previous
//
#include <hip/hip_runtime.h>

#define NTOK 8192
#define D 4096
#define CH 1024

typedef __attribute__((ext_vector_type(8))) short short8v;
typedef __attribute__((ext_vector_type(4))) float float4v;
typedef __attribute__((ext_vector_type(4))) unsigned short ushort4v;

static __device__ __forceinline__ unsigned short f2bf(float f) {
  unsigned int u = __float_as_uint(f);
  u += 0x7fff + ((u >> 16) & 1);   // round-to-nearest-even
  return (unsigned short)(u >> 16);
}

static __device__ __forceinline__ void async_cp16(const void* g, void* l) {
  __builtin_amdgcn_global_load_lds((__attribute__((address_space(1))) void*)g,
                                   (__attribute__((address_space(3))) void*)l,
                                   16, 0, 0);
}

// ---------------------------------------------------------------------------
// Kernel 1 v2: 4 tokens/block, 2048 blocks, 512 threads.
//  - Single-shot async staging of x into LDS (64 KB), ONE barrier drain
//    instead of 16 (the per-chunk barrier drained vmcnt every time, exposing
//    full HBM latency 16x).
//  - Main projection loop runs barrier-free from LDS.
//  - Phase B (x_layer) reads x from LDS instead of re-reading 128 MB from
//    global/L3.
//  - ~66 KB LDS -> 2 blocks/CU so staging of one block hides under compute
//    of the other.
// ---------------------------------------------------------------------------
__global__ __launch_bounds__(512, 4) void gates_kernel(
    const float* __restrict__ x, const float* __restrict__ rms_w,
    const float* __restrict__ Wpre, const float* __restrict__ Wpost,
    const float* __restrict__ Wres, const float* __restrict__ bpre,
    const float* __restrict__ bpost, const float* __restrict__ bres,
    const float* __restrict__ apre, const float* __restrict__ apost,
    const float* __restrict__ ares, const float* __restrict__ Wsub,
    unsigned short* __restrict__ Wb, float* __restrict__ gates_out,
    unsigned short* __restrict__ xlayer) {
  __shared__ float xbuf[4][4096];       // 64 KB, lives whole kernel
  __shared__ float logits_lds[4][24];
  __shared__ float sq_lds[4];
  __shared__ float s_lds[4];
  __shared__ float hpre_lds[4][4];

  const int tid = threadIdx.x;
  const int lane = tid & 63;
  const int w = tid >> 6;               // 0..7
  const int tok0 = blockIdx.x * 4;

  // single-shot staging: wave w stages token (w>>1), half (w&1): 8 x 1 KB
  {
    const int t = w >> 1;
    const int c0 = (w & 1) * 2048;      // float offset of this wave's half
    const float* src = x + (size_t)(tok0 + t) * D + c0 + lane * 4;
#pragma unroll
    for (int j = 0; j < 8; ++j)
      async_cp16(src + j * 256, (void*)&xbuf[t][c0 + j * 256]);
  }

  // fold prep_wsub (overlaps staging): blocks 0..1023 convert 1 KB of Wsub
  if (blockIdx.x < 1024) {
    int i = blockIdx.x * 1024 + tid * 2;
    float2 v = *(const float2*)(Wsub + i);
    unsigned int packed = (unsigned int)f2bf(v.x) | ((unsigned int)f2bf(v.y) << 16);
    *(unsigned int*)(Wb + i) = packed;
  }

  const float* Wp[3];
#pragma unroll
  for (int g = 0; g < 3; ++g) {
    int gg = w * 3 + g;
    Wp[g] = (gg < 4) ? (Wpre + gg * D)
          : (gg < 8) ? (Wpost + (gg - 4) * D)
                     : (Wres + (gg - 8) * D);
  }

  float acc[3][4];
#pragma unroll
  for (int g = 0; g < 3; ++g)
#pragma unroll
    for (int t = 0; t < 4; ++t) acc[g][t] = 0.f;
  float sq = 0.f;

  __syncthreads();   // one drain for all 64 KB of staging

  // barrier-free main loop: weights stream from L2, x from LDS
#pragma unroll 4
  for (int chk = 0; chk < 16; ++chk) {
    const int cb = chk * 256 + lane * 4;
    float4 w4[3];
#pragma unroll
    for (int g = 0; g < 3; ++g) w4[g] = *(const float4*)(Wp[g] + cb);
    float4 r4 = *(const float4*)(rms_w + cb);
#pragma unroll
    for (int t = 0; t < 4; ++t) {
      float4 xv = *(const float4*)(&xbuf[t][cb]);
      if (w == (t << 1))
        sq += xv.x * xv.x + xv.y * xv.y + xv.z * xv.z + xv.w * xv.w;
      float4 xr;
      xr.x = xv.x * r4.x; xr.y = xv.y * r4.y; xr.z = xv.z * r4.z; xr.w = xv.w * r4.w;
#pragma unroll
      for (int g = 0; g < 3; ++g)
        acc[g][t] += xr.x * w4[g].x + xr.y * w4[g].y + xr.z * w4[g].z + xr.w * w4[g].w;
    }
  }

  // wave reductions -> LDS (wave w: 3 gate rows x 4 tokens; even waves: sumsq)
#pragma unroll
  for (int g = 0; g < 3; ++g)
#pragma unroll
    for (int t = 0; t < 4; ++t) {
      float v = acc[g][t];
      for (int off = 32; off > 0; off >>= 1) v += __shfl_xor(v, off, 64);
      if (lane == 0) logits_lds[t][w * 3 + g] = v;
    }
  if ((w & 1) == 0) {
    float v = sq;
    for (int off = 32; off > 0; off >>= 1) v += __shfl_xor(v, off, 64);
    if (lane == 0) sq_lds[w >> 1] = v;
  }
  __syncthreads();

  // per-token cheap scalar math (threads 0..3): rms scale + sigmoids
  if (tid < 4) {
    const int t = tid;
    float s = rsqrtf(sq_lds[t] * (1.0f / 4096.0f) + 1e-8f);
    s_lds[t] = s;
    float a_pre = apre[0], a_post = apost[0];

    float hp[4];
    float sum_p = 1e-6f;
#pragma unroll
    for (int i = 0; i < 4; ++i) {
      float z = a_pre * (s * logits_lds[t][i]) + bpre[i];
      hp[i] = 1.0f / (1.0f + __expf(-z));
      sum_p += hp[i];
    }
    float inv_p = 1.0f / sum_p;
#pragma unroll
    for (int i = 0; i < 4; ++i) hpre_lds[t][i] = hp[i] * inv_p;

    float* go = gates_out + (size_t)(tok0 + t) * 20;
    float hq[4];
    float sum_q = 1e-6f;
#pragma unroll
    for (int i = 0; i < 4; ++i) {
      float z = a_post * (s * logits_lds[t][4 + i]) + bpost[i];
      hq[i] = 2.0f / (1.0f + __expf(-z));
      sum_q += hq[i];
    }
    float inv_q = 1.0f / sum_q;
#pragma unroll
    for (int i = 0; i < 4; ++i) go[i] = hq[i] * inv_q;
  }
  __syncthreads();

  // phase B: x_layer from LDS (no global re-read). 1024 float4-slots total.
  auto phB = [&](int s) {
    const int t = s >> 8;
    const int c4 = (s & 255) * 4;
    const float h0 = hpre_lds[t][0], h1 = hpre_lds[t][1];
    const float h2 = hpre_lds[t][2], h3 = hpre_lds[t][3];
    const float4 x0 = *(const float4*)&xbuf[t][c4];
    const float4 x1 = *(const float4*)&xbuf[t][1024 + c4];
    const float4 x2 = *(const float4*)&xbuf[t][2048 + c4];
    const float4 x3 = *(const float4*)&xbuf[t][3072 + c4];
    ushort4v o;
    o.x = f2bf(h0 * x0.x + h1 * x1.x + h2 * x2.x + h3 * x3.x);
    o.y = f2bf(h0 * x0.y + h1 * x1.y + h2 * x2.y + h3 * x3.y);
    o.z = f2bf(h0 * x0.z + h1 * x1.z + h2 * x2.z + h3 * x3.z);
    o.w = f2bf(h0 * x0.w + h1 * x1.w + h2 * x2.w + h3 * x3.w);
    *(ushort4v*)(xlayer + (size_t)(tok0 + t) * CH + c4) = o;
  };

  if (w == 0) {
    // sinkhorn (16 lanes, 4 tok x 4 rows); waves 1..7 do phase B meanwhile
    if (lane < 16) {
      const int t = lane >> 2;
      const int r = lane & 3;
      const float s = s_lds[t];
      const float a_res = ares[0];
      float Zrow[4], Zcol[4];
#pragma unroll
      for (int j = 0; j < 4; ++j) {
        Zrow[j] = (a_res * (s * logits_lds[t][8 + r * 4 + j]) + bres[r * 4 + j]) * 20.0f;
        Zcol[j] = (a_res * (s * logits_lds[t][8 + j * 4 + r]) + bres[j * 4 + r]) * 20.0f;
      }
      float u = 0.f, v = 0.f;
      const int base = t << 2;
      for (int it = 0; it < 20; ++it) {
        float v0 = __shfl(v, base + 0, 64), v1 = __shfl(v, base + 1, 64);
        float v2 = __shfl(v, base + 2, 64), v3 = __shfl(v, base + 3, 64);
        float a0 = Zrow[0] + v0, a1 = Zrow[1] + v1, a2 = Zrow[2] + v2, a3 = Zrow[3] + v3;
        float m = fmaxf(fmaxf(a0, a1), fmaxf(a2, a3));
        float sm = __expf(a0 - m) + __expf(a1 - m) + __expf(a2 - m) + __expf(a3 - m);
        u = -(m + __logf(sm));
        float u0 = __shfl(u, base + 0, 64), u1 = __shfl(u, base + 1, 64);
        float u2 = __shfl(u, base + 2, 64), u3 = __shfl(u, base + 3, 64);
        float b0 = Zcol[0] + u0, b1 = Zcol[1] + u1, b2 = Zcol[2] + u2, b3 = Zcol[3] + u3;
        float m2 = fmaxf(fmaxf(b0, b1), fmaxf(b2, b3));
        float sm2 = __expf(b0 - m2) + __expf(b1 - m2) + __expf(b2 - m2) + __expf(b3 - m2);
        v = -(m2 + __logf(sm2));
      }
      float v0 = __shfl(v, base + 0, 64), v1 = __shfl(v, base + 1, 64);
      float v2 = __shfl(v, base + 2, 64), v3 = __shfl(v, base + 3, 64);
      float* go = gates_out + (size_t)(tok0 + t) * 20;
      go[4 + r * 4 + 0] = __expf(Zrow[0] + u + v0);
      go[4 + r * 4 + 1] = __expf(Zrow[1] + u + v1);
      go[4 + r * 4 + 2] = __expf(Zrow[2] + u + v2);
      go[4 + r * 4 + 3] = __expf(Zrow[3] + u + v3);
    }
    phB(896 + lane);
    phB(960 + lane);
  } else {
    phB(tid - 64);
    phB(tid + 384);   // (tid-64) + 448
  }
}

// ---------------------------------------------------------------------------
// Kernel 2 v2: y = x_layer @ W_sub^T (bf16 MFMA, 128x128, BK=64, dbuf) with
// register-direct epilogue (no y LDS round-trip, 2 fewer barriers).
// LDS = 64 KB staging + 10 KB gates = 75,776 B -> 2 blocks/CU.
// ---------------------------------------------------------------------------
__global__ __launch_bounds__(256, 2) void gemm_epi(
    const unsigned short* __restrict__ A,   // x_layer bf16 [8192][1024]
    const unsigned short* __restrict__ B,   // W_sub  bf16 [1024][1024]
    const float* __restrict__ x,            // x_streams fp32
    const float* __restrict__ gates,        // [8192][20]: Hpost_w[4], Hres[16]
    float* __restrict__ out) {
  __shared__ __align__(16) unsigned short stg[32768];  // 64 KB: [buf][A|B]
  __shared__ float hpost_sm[128][4];                   // 2 KB, 16B-aligned rows
  __shared__ float hres_sm[128][16];                   // 8 KB, 64B-aligned rows

  const int tid = threadIdx.x;
  const int lane = tid & 63;
  const int w = tid >> 6;
  const int n0 = blockIdx.x * 128;
  const int m0 = blockIdx.y * 128;

  // gates -> split LDS arrays (aligned float4 rows)
  {
    const int r = tid >> 1, half = tid & 1;
    const float* gp = gates + (size_t)(m0 + r) * 20 + half * 10;
#pragma unroll
    for (int j = 0; j < 10; ++j) {
      int jj = half * 10 + j;
      float v = gp[j];
      if (jj < 4) hpost_sm[r][jj] = v;
      else        hres_sm[r][jj - 4] = v;
    }
  }

  float4v accf[4][4];
#pragma unroll
  for (int mi = 0; mi < 4; ++mi)
#pragma unroll
    for (int ni = 0; ni < 4; ++ni) {
      accf[mi][ni].x = 0.f; accf[mi][ni].y = 0.f;
      accf[mi][ni].z = 0.f; accf[mi][ni].w = 0.f;
    }

  const int wm = (w >> 1) * 64;
  const int wn = (w & 1) * 64;
  const int srow = lane >> 3;   // staging: 8 rows per 1KB chunk
  const int sslot = lane & 7;   // 8 x 16B slots per 128B row

#define STAGE(KT, BUF)                                                        \
  {                                                                           \
    const int k0s = (KT) * 64;                                                \
    unsigned short* As = stg + (BUF) * 8192;                                  \
    unsigned short* Bs = stg + 16384 + (BUF) * 8192;                          \
    _Pragma("unroll")                                                         \
    for (int i = 0; i < 4; ++i) {                                             \
      int chunk = w * 4 + i;                                                  \
      int row = chunk * 8 + srow;                                             \
      int qg = sslot ^ (row & 7);                                             \
      async_cp16(A + (size_t)(m0 + row) * 1024 + k0s + qg * 8,                \
                 (void*)(As + chunk * 512));                                  \
      async_cp16(B + (size_t)(n0 + row) * 1024 + k0s + qg * 8,                \
                 (void*)(Bs + chunk * 512));                                  \
    }                                                                         \
  }

  STAGE(0, 0);
  __syncthreads();

  for (int kt = 0; kt < 16; ++kt) {
    const int cur = kt & 1;
    if (kt < 15) STAGE(kt + 1, cur ^ 1);
    const unsigned short* As = stg + cur * 8192;
    const unsigned short* Bs = stg + 16384 + cur * 8192;
#pragma unroll
    for (int kk = 0; kk < 2; ++kk) {
      short8v a[4], b[4];
#pragma unroll
      for (int mi = 0; mi < 4; ++mi) {
        int row = wm + mi * 16 + (lane & 15);
        int q = (kk * 4 + (lane >> 4)) ^ (row & 7);
        a[mi] = *(const short8v*)(As + row * 64 + q * 8);
      }
#pragma unroll
      for (int ni = 0; ni < 4; ++ni) {
        int row = wn + ni * 16 + (lane & 15);
        int q = (kk * 4 + (lane >> 4)) ^ (row & 7);
        b[ni] = *(const short8v*)(Bs + row * 64 + q * 8);
      }
#pragma unroll
      for (int mi = 0; mi < 4; ++mi)
#pragma unroll
        for (int ni = 0; ni < 4; ++ni)
          accf[mi][ni] = __builtin_amdgcn_mfma_f32_16x16x32_bf16(
              a[mi], b[ni], accf[mi][ni], 0, 0, 0);
    }
    __syncthreads();
  }

  // register-direct epilogue: C/D layout row = wm+mi*16+(lane>>4)*4+r,
  // col = wn+ni*16+(lane&15). 4B/lane in 16-lane runs = 64B segments.
  const int rg = (lane >> 4) * 4;
  const int cl = lane & 15;
#pragma unroll
  for (int mi = 0; mi < 4; ++mi) {
#pragma unroll
    for (int r = 0; r < 4; ++r) {
      const int row = wm + mi * 16 + rg + r;
      const size_t t = (size_t)(m0 + row);
      const float4 hq = *(const float4*)(&hpost_sm[row][0]);
      const float4 h0 = *(const float4*)(&hres_sm[row][0]);
      const float4 h1 = *(const float4*)(&hres_sm[row][4]);
      const float4 h2 = *(const float4*)(&hres_sm[row][8]);
      const float4 h3 = *(const float4*)(&hres_sm[row][12]);
      const float* xp = x + t * 4096 + n0 + wn + cl;
      float* op = out + t * 4096 + n0 + wn + cl;
#pragma unroll
      for (int ni = 0; ni < 4; ++ni) {
        const int c = ni * 16;
        float x0 = xp[c], x1 = xp[c + 1024], x2 = xp[c + 2048], x3 = xp[c + 3072];
        float y = accf[mi][ni][r];
        op[c]        = x0 * h0.x + x1 * h0.y + x2 * h0.z + x3 * h0.w + hq.x * y;
        op[c + 1024] = x0 * h1.x + x1 * h1.y + x2 * h1.z + x3 * h1.w + hq.y * y;
        op[c + 2048] = x0 * h2.x + x1 * h2.y + x2 * h2.z + x3 * h2.w + hq.z * y;
        op[c + 3072] = x0 * h3.x + x1 * h3.y + x2 * h3.z + x3 * h3.w + hq.w * y;
      }
    }
  }
}

extern "C" void kernel_launch(void* const* d_in, const int* in_sizes, int n_in,
                              void* d_out, int out_size, void* d_ws, size_t ws_size,
                              hipStream_t stream) {
  const float* x     = (const float*)d_in[0];
  const float* rms_w = (const float*)d_in[1];
  const float* Wpre  = (const float*)d_in[2];
  const float* Wpost = (const float*)d_in[3];
  const float* Wres  = (const float*)d_in[4];
  const float* bpre  = (const float*)d_in[5];
  const float* bpost = (const float*)d_in[6];
  const float* bres  = (const float*)d_in[7];
  const float* apre  = (const float*)d_in[8];
  const float* apost = (const float*)d_in[9];
  const float* ares  = (const float*)d_in[10];
  const float* Wsub  = (const float*)d_in[11];
  float* out = (float*)d_out;

  char* ws = (char*)d_ws;
  float* gates           = (float*)ws;                         // 640 KB
  unsigned short* Wb     = (unsigned short*)(ws + (1 << 20));  // 2 MB
  unsigned short* xlayer = (unsigned short*)(ws + (4 << 20));  // 16 MB

  gates_kernel<<<2048, 512, 0, stream>>>(x, rms_w, Wpre, Wpost, Wres, bpre,
                                         bpost, bres, apre, apost, ares,
                                         Wsub, Wb, gates, xlayer);
  gemm_epi<<<dim3(8, 64), 256, 0, stream>>>(xlayer, Wb, x, gates, out);
}

// Round 2
// 362.830 us; speedup vs baseline: 1.0567x; 1.0361x over previous
//
#include <hip/hip_runtime.h>

#define NTOK 8192
#define D 4096
#define CH 1024

typedef __attribute__((ext_vector_type(8))) short short8v;
typedef __attribute__((ext_vector_type(4))) float float4v;
typedef __attribute__((ext_vector_type(4))) unsigned short ushort4v;

static __device__ __forceinline__ unsigned short f2bf(float f) {
  unsigned int u = __float_as_uint(f);
  u += 0x7fff + ((u >> 16) & 1);   // round-to-nearest-even
  return (unsigned short)(u >> 16);
}

static __device__ __forceinline__ float bf2f(unsigned short u) {
  return __uint_as_float(((unsigned int)u) << 16);
}

static __device__ __forceinline__ void async_cp16(const void* g, void* l) {
  __builtin_amdgcn_global_load_lds((__attribute__((address_space(1))) void*)g,
                                   (__attribute__((address_space(3))) void*)l,
                                   16, 0, 0);
}

// ---------------------------------------------------------------------------
// Kernel 1 v3: 8 tokens/block, 1024 blocks, 512 threads.
//  - Round-1 lesson: per-block weight re-read (24 rows x 16 KB from L2) is a
//    first-order cost; 2048 blocks doubled it vs round 0. Back to 1024 blocks.
//  - x staged to LDS as bf16 (64 KB for 8 tokens -> still 2 blocks/CU) via
//    register path; sumsq accumulated in fp32 DURING staging (free, and keeps
//    rms scale full precision).
//  - Single barrier after staging; barrier-free main loop (weights from L2,
//    x from LDS); rms_w folded into weights once per chunk instead of per
//    token (32 ops -> 12).
//  - Phase B reads bf16 x from LDS; sinkhorn tail on wave 0 overlaps waves
//    1..7 doing phase B.
// ---------------------------------------------------------------------------
__global__ __launch_bounds__(512, 4) void gates_kernel(
    const float* __restrict__ x, const float* __restrict__ rms_w,
    const float* __restrict__ Wpre, const float* __restrict__ Wpost,
    const float* __restrict__ Wres, const float* __restrict__ bpre,
    const float* __restrict__ bpost, const float* __restrict__ bres,
    const float* __restrict__ apre, const float* __restrict__ apost,
    const float* __restrict__ ares, const float* __restrict__ Wsub,
    unsigned short* __restrict__ Wb, float* __restrict__ gates_out,
    unsigned short* __restrict__ xlayer) {
  __shared__ unsigned short xb[8][4096];   // 64 KB bf16 x
  __shared__ float logits_lds[8][24];
  __shared__ float sq_lds[8];
  __shared__ float s_lds[8];
  __shared__ float hpre_lds[8][4];

  const int tid = threadIdx.x;
  const int lane = tid & 63;
  const int w = tid >> 6;               // 0..7 = token within block
  const int tok0 = blockIdx.x * 8;

  // fold prep_wsub: each of the 1024 blocks converts 1 KB of Wsub to bf16
  {
    int i = blockIdx.x * 1024 + tid * 2;
    float2 v = *(const float2*)(Wsub + i);
    unsigned int packed = (unsigned int)f2bf(v.x) | ((unsigned int)f2bf(v.y) << 16);
    *(unsigned int*)(Wb + i) = packed;
  }

  // stage token w: fp32 global -> sumsq (fp32) + bf16 pack -> LDS
  {
    const float* src = x + (size_t)(tok0 + w) * D + lane * 4;
    float sq = 0.f;
#pragma unroll
    for (int j = 0; j < 16; ++j) {
      float4 v = *(const float4*)(src + j * 256);
      sq += v.x * v.x + v.y * v.y + v.z * v.z + v.w * v.w;
      uint2 p;
      p.x = (unsigned int)f2bf(v.x) | ((unsigned int)f2bf(v.y) << 16);
      p.y = (unsigned int)f2bf(v.z) | ((unsigned int)f2bf(v.w) << 16);
      *(uint2*)(&xb[w][j * 256 + lane * 4]) = p;
    }
    for (int off = 32; off > 0; off >>= 1) sq += __shfl_xor(sq, off, 64);
    if (lane == 0) sq_lds[w] = sq;
  }

  const float* Wp[3];
#pragma unroll
  for (int g = 0; g < 3; ++g) {
    int gg = w * 3 + g;
    Wp[g] = (gg < 4) ? (Wpre + gg * D)
          : (gg < 8) ? (Wpost + (gg - 4) * D)
                     : (Wres + (gg - 8) * D);
  }

  float acc[3][8];
#pragma unroll
  for (int g = 0; g < 3; ++g)
#pragma unroll
    for (int t = 0; t < 8; ++t) acc[g][t] = 0.f;

  __syncthreads();   // staging complete (ds_writes visible block-wide)

  // barrier-free main loop: weights stream from L2, x from LDS (bf16)
#pragma unroll 4
  for (int chk = 0; chk < 16; ++chk) {
    const int cb = chk * 256 + lane * 4;
    float4 r4 = *(const float4*)(rms_w + cb);
    float4 wr[3];
#pragma unroll
    for (int g = 0; g < 3; ++g) {
      float4 w4 = *(const float4*)(Wp[g] + cb);
      wr[g].x = w4.x * r4.x; wr[g].y = w4.y * r4.y;
      wr[g].z = w4.z * r4.z; wr[g].w = w4.w * r4.w;
    }
#pragma unroll
    for (int t = 0; t < 8; ++t) {
      ushort4v xv = *(const ushort4v*)(&xb[t][cb]);
      float x0 = bf2f(xv.x), x1 = bf2f(xv.y), x2 = bf2f(xv.z), x3 = bf2f(xv.w);
#pragma unroll
      for (int g = 0; g < 3; ++g)
        acc[g][t] += x0 * wr[g].x + x1 * wr[g].y + x2 * wr[g].z + x3 * wr[g].w;
    }
  }

  // wave reductions -> LDS (wave w: 3 gate rows x 8 tokens)
#pragma unroll
  for (int g = 0; g < 3; ++g)
#pragma unroll
    for (int t = 0; t < 8; ++t) {
      float v = acc[g][t];
      for (int off = 32; off > 0; off >>= 1) v += __shfl_xor(v, off, 64);
      if (lane == 0) logits_lds[t][w * 3 + g] = v;
    }
  __syncthreads();

  // per-token cheap scalar math (threads 0..7): rms scale + sigmoids
  if (tid < 8) {
    const int t = tid;
    float s = rsqrtf(sq_lds[t] * (1.0f / 4096.0f) + 1e-8f);
    s_lds[t] = s;
    float a_pre = apre[0], a_post = apost[0];

    float hp[4];
    float sum_p = 1e-6f;
#pragma unroll
    for (int i = 0; i < 4; ++i) {
      float z = a_pre * (s * logits_lds[t][i]) + bpre[i];
      hp[i] = 1.0f / (1.0f + __expf(-z));
      sum_p += hp[i];
    }
    float inv_p = 1.0f / sum_p;
#pragma unroll
    for (int i = 0; i < 4; ++i) hpre_lds[t][i] = hp[i] * inv_p;

    float* go = gates_out + (size_t)(tok0 + t) * 20;
    float hq[4];
    float sum_q = 1e-6f;
#pragma unroll
    for (int i = 0; i < 4; ++i) {
      float z = a_post * (s * logits_lds[t][4 + i]) + bpost[i];
      hq[i] = 2.0f / (1.0f + __expf(-z));
      sum_q += hq[i];
    }
    float inv_q = 1.0f / sum_q;
#pragma unroll
    for (int i = 0; i < 4; ++i) go[i] = hq[i] * inv_q;
  }
  __syncthreads();

  // phase B: x_layer from bf16 LDS. 2048 ushort4-slots total.
  auto phB = [&](int sI) {
    const int t = sI >> 8;
    const int c4 = (sI & 255) * 4;
    const float h0 = hpre_lds[t][0], h1 = hpre_lds[t][1];
    const float h2 = hpre_lds[t][2], h3 = hpre_lds[t][3];
    ushort4v v0 = *(const ushort4v*)&xb[t][c4];
    ushort4v v1 = *(const ushort4v*)&xb[t][1024 + c4];
    ushort4v v2 = *(const ushort4v*)&xb[t][2048 + c4];
    ushort4v v3 = *(const ushort4v*)&xb[t][3072 + c4];
    ushort4v o;
    o.x = f2bf(h0 * bf2f(v0.x) + h1 * bf2f(v1.x) + h2 * bf2f(v2.x) + h3 * bf2f(v3.x));
    o.y = f2bf(h0 * bf2f(v0.y) + h1 * bf2f(v1.y) + h2 * bf2f(v2.y) + h3 * bf2f(v3.y));
    o.z = f2bf(h0 * bf2f(v0.z) + h1 * bf2f(v1.z) + h2 * bf2f(v2.z) + h3 * bf2f(v3.z));
    o.w = f2bf(h0 * bf2f(v0.w) + h1 * bf2f(v1.w) + h2 * bf2f(v2.w) + h3 * bf2f(v3.w));
    *(ushort4v*)(xlayer + (size_t)(tok0 + t) * CH + c4) = o;
  };

  if (w == 0) {
    // sinkhorn (32 lanes: 8 tok x 4 rows); waves 1..7 run phase B meanwhile
    if (lane < 32) {
      const int t = lane >> 2;
      const int r = lane & 3;
      const float s = s_lds[t];
      const float a_res = ares[0];
      float Zrow[4], Zcol[4];
#pragma unroll
      for (int j = 0; j < 4; ++j) {
        Zrow[j] = (a_res * (s * logits_lds[t][8 + r * 4 + j]) + bres[r * 4 + j]) * 20.0f;
        Zcol[j] = (a_res * (s * logits_lds[t][8 + j * 4 + r]) + bres[j * 4 + r]) * 20.0f;
      }
      float u = 0.f, v = 0.f;
      const int base = t << 2;
      for (int it = 0; it < 20; ++it) {
        float v0 = __shfl(v, base + 0, 64), v1 = __shfl(v, base + 1, 64);
        float v2 = __shfl(v, base + 2, 64), v3 = __shfl(v, base + 3, 64);
        float a0 = Zrow[0] + v0, a1 = Zrow[1] + v1, a2 = Zrow[2] + v2, a3 = Zrow[3] + v3;
        float m = fmaxf(fmaxf(a0, a1), fmaxf(a2, a3));
        float sm = __expf(a0 - m) + __expf(a1 - m) + __expf(a2 - m) + __expf(a3 - m);
        u = -(m + __logf(sm));
        float u0 = __shfl(u, base + 0, 64), u1 = __shfl(u, base + 1, 64);
        float u2 = __shfl(u, base + 2, 64), u3 = __shfl(u, base + 3, 64);
        float b0 = Zcol[0] + u0, b1 = Zcol[1] + u1, b2 = Zcol[2] + u2, b3 = Zcol[3] + u3;
        float m2 = fmaxf(fmaxf(b0, b1), fmaxf(b2, b3));
        float sm2 = __expf(b0 - m2) + __expf(b1 - m2) + __expf(b2 - m2) + __expf(b3 - m2);
        v = -(m2 + __logf(sm2));
      }
      float v0 = __shfl(v, base + 0, 64), v1 = __shfl(v, base + 1, 64);
      float v2 = __shfl(v, base + 2, 64), v3 = __shfl(v, base + 3, 64);
      float* go = gates_out + (size_t)(tok0 + t) * 20;
      go[4 + r * 4 + 0] = __expf(Zrow[0] + u + v0);
      go[4 + r * 4 + 1] = __expf(Zrow[1] + u + v1);
      go[4 + r * 4 + 2] = __expf(Zrow[2] + u + v2);
      go[4 + r * 4 + 3] = __expf(Zrow[3] + u + v3);
    }
    // wave 0's share of phase B: last 256 slots
#pragma unroll
    for (int i = 0; i < 4; ++i) phB(1792 + i * 64 + lane);
  } else {
    // waves 1..7: 448 threads x 4 slots = 1792 slots
    const int b = tid - 64;
#pragma unroll
    for (int i = 0; i < 4; ++i) phB(b + i * 448);
  }
}

// ---------------------------------------------------------------------------
// Kernel 2 (unchanged from round 1): y = x_layer @ W_sub^T (bf16 MFMA,
// 128x128, BK=64, dbuf) with register-direct epilogue.
// ---------------------------------------------------------------------------
__global__ __launch_bounds__(256, 2) void gemm_epi(
    const unsigned short* __restrict__ A,   // x_layer bf16 [8192][1024]
    const unsigned short* __restrict__ B,   // W_sub  bf16 [1024][1024]
    const float* __restrict__ x,            // x_streams fp32
    const float* __restrict__ gates,        // [8192][20]: Hpost_w[4], Hres[16]
    float* __restrict__ out) {
  __shared__ __align__(16) unsigned short stg[32768];  // 64 KB: [buf][A|B]
  __shared__ float hpost_sm[128][4];
  __shared__ float hres_sm[128][16];

  const int tid = threadIdx.x;
  const int lane = tid & 63;
  const int w = tid >> 6;
  const int n0 = blockIdx.x * 128;
  const int m0 = blockIdx.y * 128;

  {
    const int r = tid >> 1, half = tid & 1;
    const float* gp = gates + (size_t)(m0 + r) * 20 + half * 10;
#pragma unroll
    for (int j = 0; j < 10; ++j) {
      int jj = half * 10 + j;
      float v = gp[j];
      if (jj < 4) hpost_sm[r][jj] = v;
      else        hres_sm[r][jj - 4] = v;
    }
  }

  float4v accf[4][4];
#pragma unroll
  for (int mi = 0; mi < 4; ++mi)
#pragma unroll
    for (int ni = 0; ni < 4; ++ni) {
      accf[mi][ni].x = 0.f; accf[mi][ni].y = 0.f;
      accf[mi][ni].z = 0.f; accf[mi][ni].w = 0.f;
    }

  const int wm = (w >> 1) * 64;
  const int wn = (w & 1) * 64;
  const int srow = lane >> 3;
  const int sslot = lane & 7;

#define STAGE(KT, BUF)                                                        \
  {                                                                           \
    const int k0s = (KT) * 64;                                                \
    unsigned short* As = stg + (BUF) * 8192;                                  \
    unsigned short* Bs = stg + 16384 + (BUF) * 8192;                          \
    _Pragma("unroll")                                                         \
    for (int i = 0; i < 4; ++i) {                                             \
      int chunk = w * 4 + i;                                                  \
      int row = chunk * 8 + srow;                                             \
      int qg = sslot ^ (row & 7);                                             \
      async_cp16(A + (size_t)(m0 + row) * 1024 + k0s + qg * 8,                \
                 (void*)(As + chunk * 512));                                  \
      async_cp16(B + (size_t)(n0 + row) * 1024 + k0s + qg * 8,                \
                 (void*)(Bs + chunk * 512));                                  \
    }                                                                         \
  }

  STAGE(0, 0);
  __syncthreads();

  for (int kt = 0; kt < 16; ++kt) {
    const int cur = kt & 1;
    if (kt < 15) STAGE(kt + 1, cur ^ 1);
    const unsigned short* As = stg + cur * 8192;
    const unsigned short* Bs = stg + 16384 + cur * 8192;
#pragma unroll
    for (int kk = 0; kk < 2; ++kk) {
      short8v a[4], b[4];
#pragma unroll
      for (int mi = 0; mi < 4; ++mi) {
        int row = wm + mi * 16 + (lane & 15);
        int q = (kk * 4 + (lane >> 4)) ^ (row & 7);
        a[mi] = *(const short8v*)(As + row * 64 + q * 8);
      }
#pragma unroll
      for (int ni = 0; ni < 4; ++ni) {
        int row = wn + ni * 16 + (lane & 15);
        int q = (kk * 4 + (lane >> 4)) ^ (row & 7);
        b[ni] = *(const short8v*)(Bs + row * 64 + q * 8);
      }
#pragma unroll
      for (int mi = 0; mi < 4; ++mi)
#pragma unroll
        for (int ni = 0; ni < 4; ++ni)
          accf[mi][ni] = __builtin_amdgcn_mfma_f32_16x16x32_bf16(
              a[mi], b[ni], accf[mi][ni], 0, 0, 0);
    }
    __syncthreads();
  }

  const int rg = (lane >> 4) * 4;
  const int cl = lane & 15;
#pragma unroll
  for (int mi = 0; mi < 4; ++mi) {
#pragma unroll
    for (int r = 0; r < 4; ++r) {
      const int row = wm + mi * 16 + rg + r;
      const size_t t = (size_t)(m0 + row);
      const float4 hq = *(const float4*)(&hpost_sm[row][0]);
      const float4 h0 = *(const float4*)(&hres_sm[row][0]);
      const float4 h1 = *(const float4*)(&hres_sm[row][4]);
      const float4 h2 = *(const float4*)(&hres_sm[row][8]);
      const float4 h3 = *(const float4*)(&hres_sm[row][12]);
      const float* xp = x + t * 4096 + n0 + wn + cl;
      float* op = out + t * 4096 + n0 + wn + cl;
#pragma unroll
      for (int ni = 0; ni < 4; ++ni) {
        const int c = ni * 16;
        float x0 = xp[c], x1 = xp[c + 1024], x2 = xp[c + 2048], x3 = xp[c + 3072];
        float y = accf[mi][ni][r];
        op[c]        = x0 * h0.x + x1 * h0.y + x2 * h0.z + x3 * h0.w + hq.x * y;
        op[c + 1024] = x0 * h1.x + x1 * h1.y + x2 * h1.z + x3 * h1.w + hq.y * y;
        op[c + 2048] = x0 * h2.x + x1 * h2.y + x2 * h2.z + x3 * h2.w + hq.z * y;
        op[c + 3072] = x0 * h3.x + x1 * h3.y + x2 * h3.z + x3 * h3.w + hq.w * y;
      }
    }
  }
}

extern "C" void kernel_launch(void* const* d_in, const int* in_sizes, int n_in,
                              void* d_out, int out_size, void* d_ws, size_t ws_size,
                              hipStream_t stream) {
  const float* x     = (const float*)d_in[0];
  const float* rms_w = (const float*)d_in[1];
  const float* Wpre  = (const float*)d_in[2];
  const float* Wpost = (const float*)d_in[3];
  const float* Wres  = (const float*)d_in[4];
  const float* bpre  = (const float*)d_in[5];
  const float* bpost = (const float*)d_in[6];
  const float* bres  = (const float*)d_in[7];
  const float* apre  = (const float*)d_in[8];
  const float* apost = (const float*)d_in[9];
  const float* ares  = (const float*)d_in[10];
  const float* Wsub  = (const float*)d_in[11];
  float* out = (float*)d_out;

  char* ws = (char*)d_ws;
  float* gates           = (float*)ws;                         // 640 KB
  unsigned short* Wb     = (unsigned short*)(ws + (1 << 20));  // 2 MB
  unsigned short* xlayer = (unsigned short*)(ws + (4 << 20));  // 16 MB

  gates_kernel<<<1024, 512, 0, stream>>>(x, rms_w, Wpre, Wpost, Wres, bpre,
                                         bpost, bres, apre, apost, ares,
                                         Wsub, Wb, gates, xlayer);
  gemm_epi<<<dim3(8, 64), 256, 0, stream>>>(xlayer, Wb, x, gates, out);
}

// Round 3
// 350.104 us; speedup vs baseline: 1.0951x; 1.0363x over previous
//
#include <hip/hip_runtime.h>

#define NTOK 8192
#define D 4096
#define CH 1024

typedef __attribute__((ext_vector_type(8))) short short8v;
typedef __attribute__((ext_vector_type(4))) float float4v;
typedef __attribute__((ext_vector_type(4))) unsigned short ushort4v;
typedef __attribute__((ext_vector_type(8))) unsigned short ushort8v;

static __device__ __forceinline__ unsigned short f2bf(float f) {
  unsigned int u = __float_as_uint(f);
  u += 0x7fff + ((u >> 16) & 1);   // round-to-nearest-even
  return (unsigned short)(u >> 16);
}

static __device__ __forceinline__ float bf2f(unsigned short u) {
  return __uint_as_float(((unsigned int)u) << 16);
}

static __device__ __forceinline__ void async_cp16(const void* g, void* l) {
  __builtin_amdgcn_global_load_lds((__attribute__((address_space(1))) void*)g,
                                   (__attribute__((address_space(3))) void*)l,
                                   16, 0, 0);
}

// ---------------------------------------------------------------------------
// Kernel 0 (new): weight prep. Wg = bf16[32][4096] gate weights with rms_w
// folded (rows 24..31 zero); Wb = bf16 Wsub. ~10 MB traffic, ~3 us.
// ---------------------------------------------------------------------------
__global__ __launch_bounds__(256) void prep_kernel(
    const float* __restrict__ Wpre, const float* __restrict__ Wpost,
    const float* __restrict__ Wres, const float* __restrict__ rms_w,
    const float* __restrict__ Wsub, unsigned short* __restrict__ Wg,
    unsigned short* __restrict__ Wb) {
  const int bid = blockIdx.x;
  if (bid < 2048) {
    int i = bid * 512 + threadIdx.x * 2;
    float2 v = *(const float2*)(Wsub + i);
    unsigned int packed = (unsigned int)f2bf(v.x) | ((unsigned int)f2bf(v.y) << 16);
    *(unsigned int*)(Wb + i) = packed;
  } else {
    int j = (bid - 2048) * 512 + threadIdx.x * 2;
    int g = j >> 12;
    int k = j & 4095;
    float2 r = *(const float2*)(rms_w + k);
    float2 wv;
    if (g < 4)       wv = *(const float2*)(Wpre + g * 4096 + k);
    else if (g < 8)  wv = *(const float2*)(Wpost + (g - 4) * 4096 + k);
    else if (g < 24) wv = *(const float2*)(Wres + (g - 8) * 4096 + k);
    else             { wv.x = 0.f; wv.y = 0.f; }
    unsigned int packed = (unsigned int)f2bf(wv.x * r.x) |
                          ((unsigned int)f2bf(wv.y * r.y) << 16);
    *(unsigned int*)(Wg + g * 4096 + k) = packed;
  }
}

// ---------------------------------------------------------------------------
// Kernel 1 v4: MFMA projection. 8 tokens/block, 1024 blocks, 512 threads.
//  - Round-2 lesson: scalar-FMA projection has a ~35 us VALU floor. The
//    projection is a [T x 4096] @ [4096 x 32] GEMM -> use mfma 16x16x32.
//  - K-split across waves: wave w owns k in [w*512,(w+1)*512). It stages its
//    own strip (x fp32 -> sumsq fp32 -> bf16 -> LDS, XOR-granule swizzle) and
//    MFMAs only its own writes -> ZERO barriers in the main loop.
//  - A-frag rows 8..15 duplicate tokens 0..7 (M=8<16); dup rows land in
//    discarded acc rows.
//  - B-frags read directly from L2-resident Wg bf16 (rms pre-folded).
//  - One barrier, cross-wave logit/sumsq reduce, then round-2 tail
//    (sigmoids, sinkhorn on wave 0, phase B from swizzled bf16 LDS).
// ---------------------------------------------------------------------------
__global__ __launch_bounds__(512, 4) void gates_kernel(
    const float* __restrict__ x, const unsigned short* __restrict__ Wg,
    const float* __restrict__ bpre, const float* __restrict__ bpost,
    const float* __restrict__ bres, const float* __restrict__ apre,
    const float* __restrict__ apost, const float* __restrict__ ares,
    float* __restrict__ gates_out, unsigned short* __restrict__ xlayer) {
  __shared__ __align__(16) unsigned short xb[8][4096];  // 64 KB swizzled bf16
  __shared__ float pl[8][8][32];                        // 8 KB logit partials
  __shared__ float sqp[8][8];
  __shared__ float logits_lds[8][32];
  __shared__ float sq_lds[8];
  __shared__ float s_lds[8];
  __shared__ float hpre_lds[8][4];

  const int tid = threadIdx.x;
  const int lane = tid & 63;
  const int w = tid >> 6;               // 0..7 = K-strip owner
  const int tok0 = blockIdx.x * 8;

  // ---- stage own K-strip: lane l owns granule (8 floats) g = w*64+l
  {
    float sqw[8];
    const float* src0 = x + (size_t)tok0 * D + w * 512 + lane * 8;
    const int gslot = w * 64 + lane;
#pragma unroll
    for (int t = 0; t < 8; ++t) {
      const float* s = src0 + (size_t)t * D;
      float4 a4 = *(const float4*)s;
      float4 b4 = *(const float4*)(s + 4);
      sqw[t] = a4.x * a4.x + a4.y * a4.y + a4.z * a4.z + a4.w * a4.w +
               b4.x * b4.x + b4.y * b4.y + b4.z * b4.z + b4.w * b4.w;
      ushort8v p;
      p[0] = f2bf(a4.x); p[1] = f2bf(a4.y); p[2] = f2bf(a4.z); p[3] = f2bf(a4.w);
      p[4] = f2bf(b4.x); p[5] = f2bf(b4.y); p[6] = f2bf(b4.z); p[7] = f2bf(b4.w);
      *(ushort8v*)(&xb[t][(gslot ^ t) * 8]) = p;   // XOR-granule swizzle
    }
#pragma unroll
    for (int t = 0; t < 8; ++t) {
      float v = sqw[t];
      for (int off = 32; off > 0; off >>= 1) v += __shfl_xor(v, off, 64);
      if (lane == 0) sqp[w][t] = v;
    }
  }

  // ---- barrier-free MFMA over own strip (16 k-steps of 32)
  float4v acc0 = {0.f, 0.f, 0.f, 0.f};
  float4v acc1 = {0.f, 0.f, 0.f, 0.f};
  {
    const int arow = lane & 7;          // token (rows 8..15 dup 0..7)
    const int apos = lane >> 4;         // k-subgroup 0..3
    const unsigned short* bb0 =
        Wg + (size_t)(lane & 15) * D + w * 512 + apos * 8;
    const unsigned short* bb1 = bb0 + 16 * D;
#pragma unroll 4
    for (int ks = 0; ks < 16; ++ks) {
      short8v a = *(const short8v*)(
          &xb[arow][((w * 64 + ks * 4 + apos) ^ arow) * 8]);
      short8v b0 = *(const short8v*)(bb0 + ks * 32);
      short8v b1 = *(const short8v*)(bb1 + ks * 32);
      acc0 = __builtin_amdgcn_mfma_f32_16x16x32_bf16(a, b0, acc0, 0, 0, 0);
      acc1 = __builtin_amdgcn_mfma_f32_16x16x32_bf16(a, b1, acc1, 0, 0, 0);
    }
  }

  // ---- per-wave partial logits -> LDS (D layout: col=lane&15, row=(l>>4)*4+r)
  if (lane < 32) {
    const int tr = (lane >> 4) * 4;
    const int gc = lane & 15;
#pragma unroll
    for (int r = 0; r < 4; ++r) {
      pl[w][tr + r][gc] = acc0[r];
      pl[w][tr + r][16 + gc] = acc1[r];
    }
  }
  __syncthreads();

  // ---- cross-wave reduce
  if (tid < 256) {
    const int t = tid >> 5, g = tid & 31;
    float v = 0.f;
#pragma unroll
    for (int ww = 0; ww < 8; ++ww) v += pl[ww][t][g];
    logits_lds[t][g] = v;
  } else if (tid < 264) {
    const int t = tid - 256;
    float v = 0.f;
#pragma unroll
    for (int ww = 0; ww < 8; ++ww) v += sqp[ww][t];
    sq_lds[t] = v;
  }
  __syncthreads();

  // ---- per-token scalar math (threads 0..7): rms scale + sigmoids
  if (tid < 8) {
    const int t = tid;
    float s = rsqrtf(sq_lds[t] * (1.0f / 4096.0f) + 1e-8f);
    s_lds[t] = s;
    float a_pre = apre[0], a_post = apost[0];

    float hp[4];
    float sum_p = 1e-6f;
#pragma unroll
    for (int i = 0; i < 4; ++i) {
      float z = a_pre * (s * logits_lds[t][i]) + bpre[i];
      hp[i] = 1.0f / (1.0f + __expf(-z));
      sum_p += hp[i];
    }
    float inv_p = 1.0f / sum_p;
#pragma unroll
    for (int i = 0; i < 4; ++i) hpre_lds[t][i] = hp[i] * inv_p;

    float* go = gates_out + (size_t)(tok0 + t) * 20;
    float hq[4];
    float sum_q = 1e-6f;
#pragma unroll
    for (int i = 0; i < 4; ++i) {
      float z = a_post * (s * logits_lds[t][4 + i]) + bpost[i];
      hq[i] = 2.0f / (1.0f + __expf(-z));
      sum_q += hq[i];
    }
    float inv_q = 1.0f / sum_q;
#pragma unroll
    for (int i = 0; i < 4; ++i) go[i] = hq[i] * inv_q;
  }
  __syncthreads();

  // ---- phase B: x_layer from swizzled bf16 LDS. 2048 ushort4-slots.
  auto phB = [&](int sI) {
    const int t = sI >> 8;
    const int c4 = (sI & 255) * 4;
    const int bi = t * 4096 + (((c4 >> 3) ^ t) << 3) + (c4 & 7);
    const unsigned short* xr = &xb[0][0];
    const float h0 = hpre_lds[t][0], h1 = hpre_lds[t][1];
    const float h2 = hpre_lds[t][2], h3 = hpre_lds[t][3];
    ushort4v v0 = *(const ushort4v*)(xr + bi);
    ushort4v v1 = *(const ushort4v*)(xr + bi + 1024);
    ushort4v v2 = *(const ushort4v*)(xr + bi + 2048);
    ushort4v v3 = *(const ushort4v*)(xr + bi + 3072);
    ushort4v o;
    o.x = f2bf(h0 * bf2f(v0.x) + h1 * bf2f(v1.x) + h2 * bf2f(v2.x) + h3 * bf2f(v3.x));
    o.y = f2bf(h0 * bf2f(v0.y) + h1 * bf2f(v1.y) + h2 * bf2f(v2.y) + h3 * bf2f(v3.y));
    o.z = f2bf(h0 * bf2f(v0.z) + h1 * bf2f(v1.z) + h2 * bf2f(v2.z) + h3 * bf2f(v3.z));
    o.w = f2bf(h0 * bf2f(v0.w) + h1 * bf2f(v1.w) + h2 * bf2f(v2.w) + h3 * bf2f(v3.w));
    *(ushort4v*)(xlayer + (size_t)(tok0 + t) * CH + c4) = o;
  };

  if (w == 0) {
    // sinkhorn (32 lanes: 8 tok x 4 rows); waves 1..7 run phase B meanwhile
    if (lane < 32) {
      const int t = lane >> 2;
      const int r = lane & 3;
      const float s = s_lds[t];
      const float a_res = ares[0];
      float Zrow[4], Zcol[4];
#pragma unroll
      for (int j = 0; j < 4; ++j) {
        Zrow[j] = (a_res * (s * logits_lds[t][8 + r * 4 + j]) + bres[r * 4 + j]) * 20.0f;
        Zcol[j] = (a_res * (s * logits_lds[t][8 + j * 4 + r]) + bres[j * 4 + r]) * 20.0f;
      }
      float u = 0.f, v = 0.f;
      const int base = t << 2;
      for (int it = 0; it < 20; ++it) {
        float v0 = __shfl(v, base + 0, 64), v1 = __shfl(v, base + 1, 64);
        float v2 = __shfl(v, base + 2, 64), v3 = __shfl(v, base + 3, 64);
        float a0 = Zrow[0] + v0, a1 = Zrow[1] + v1, a2 = Zrow[2] + v2, a3 = Zrow[3] + v3;
        float m = fmaxf(fmaxf(a0, a1), fmaxf(a2, a3));
        float sm = __expf(a0 - m) + __expf(a1 - m) + __expf(a2 - m) + __expf(a3 - m);
        u = -(m + __logf(sm));
        float u0 = __shfl(u, base + 0, 64), u1 = __shfl(u, base + 1, 64);
        float u2 = __shfl(u, base + 2, 64), u3 = __shfl(u, base + 3, 64);
        float b0 = Zcol[0] + u0, b1 = Zcol[1] + u1, b2 = Zcol[2] + u2, b3 = Zcol[3] + u3;
        float m2 = fmaxf(fmaxf(b0, b1), fmaxf(b2, b3));
        float sm2 = __expf(b0 - m2) + __expf(b1 - m2) + __expf(b2 - m2) + __expf(b3 - m2);
        v = -(m2 + __logf(sm2));
      }
      float v0 = __shfl(v, base + 0, 64), v1 = __shfl(v, base + 1, 64);
      float v2 = __shfl(v, base + 2, 64), v3 = __shfl(v, base + 3, 64);
      float* go = gates_out + (size_t)(tok0 + t) * 20;
      go[4 + r * 4 + 0] = __expf(Zrow[0] + u + v0);
      go[4 + r * 4 + 1] = __expf(Zrow[1] + u + v1);
      go[4 + r * 4 + 2] = __expf(Zrow[2] + u + v2);
      go[4 + r * 4 + 3] = __expf(Zrow[3] + u + v3);
    }
#pragma unroll
    for (int i = 0; i < 4; ++i) phB(1792 + i * 64 + lane);
  } else {
    const int b = tid - 64;
#pragma unroll
    for (int i = 0; i < 4; ++i) phB(b + i * 448);
  }
}

// ---------------------------------------------------------------------------
// Kernel 2 (unchanged from round 2): y = x_layer @ W_sub^T (bf16 MFMA,
// 128x128, BK=64, dbuf) with register-direct epilogue.
// ---------------------------------------------------------------------------
__global__ __launch_bounds__(256, 2) void gemm_epi(
    const unsigned short* __restrict__ A,   // x_layer bf16 [8192][1024]
    const unsigned short* __restrict__ B,   // W_sub  bf16 [1024][1024]
    const float* __restrict__ x,            // x_streams fp32
    const float* __restrict__ gates,        // [8192][20]: Hpost_w[4], Hres[16]
    float* __restrict__ out) {
  __shared__ __align__(16) unsigned short stg[32768];  // 64 KB: [buf][A|B]
  __shared__ float hpost_sm[128][4];
  __shared__ float hres_sm[128][16];

  const int tid = threadIdx.x;
  const int lane = tid & 63;
  const int w = tid >> 6;
  const int n0 = blockIdx.x * 128;
  const int m0 = blockIdx.y * 128;

  {
    const int r = tid >> 1, half = tid & 1;
    const float* gp = gates + (size_t)(m0 + r) * 20 + half * 10;
#pragma unroll
    for (int j = 0; j < 10; ++j) {
      int jj = half * 10 + j;
      float v = gp[j];
      if (jj < 4) hpost_sm[r][jj] = v;
      else        hres_sm[r][jj - 4] = v;
    }
  }

  float4v accf[4][4];
#pragma unroll
  for (int mi = 0; mi < 4; ++mi)
#pragma unroll
    for (int ni = 0; ni < 4; ++ni) {
      accf[mi][ni].x = 0.f; accf[mi][ni].y = 0.f;
      accf[mi][ni].z = 0.f; accf[mi][ni].w = 0.f;
    }

  const int wm = (w >> 1) * 64;
  const int wn = (w & 1) * 64;
  const int srow = lane >> 3;
  const int sslot = lane & 7;

#define STAGE(KT, BUF)                                                        \
  {                                                                           \
    const int k0s = (KT) * 64;                                                \
    unsigned short* As = stg + (BUF) * 8192;                                  \
    unsigned short* Bs = stg + 16384 + (BUF) * 8192;                          \
    _Pragma("unroll")                                                         \
    for (int i = 0; i < 4; ++i) {                                             \
      int chunk = w * 4 + i;                                                  \
      int row = chunk * 8 + srow;                                             \
      int qg = sslot ^ (row & 7);                                             \
      async_cp16(A + (size_t)(m0 + row) * 1024 + k0s + qg * 8,                \
                 (void*)(As + chunk * 512));                                  \
      async_cp16(B + (size_t)(n0 + row) * 1024 + k0s + qg * 8,                \
                 (void*)(Bs + chunk * 512));                                  \
    }                                                                         \
  }

  STAGE(0, 0);
  __syncthreads();

  for (int kt = 0; kt < 16; ++kt) {
    const int cur = kt & 1;
    if (kt < 15) STAGE(kt + 1, cur ^ 1);
    const unsigned short* As = stg + cur * 8192;
    const unsigned short* Bs = stg + 16384 + cur * 8192;
#pragma unroll
    for (int kk = 0; kk < 2; ++kk) {
      short8v a[4], b[4];
#pragma unroll
      for (int mi = 0; mi < 4; ++mi) {
        int row = wm + mi * 16 + (lane & 15);
        int q = (kk * 4 + (lane >> 4)) ^ (row & 7);
        a[mi] = *(const short8v*)(As + row * 64 + q * 8);
      }
#pragma unroll
      for (int ni = 0; ni < 4; ++ni) {
        int row = wn + ni * 16 + (lane & 15);
        int q = (kk * 4 + (lane >> 4)) ^ (row & 7);
        b[ni] = *(const short8v*)(Bs + row * 64 + q * 8);
      }
#pragma unroll
      for (int mi = 0; mi < 4; ++mi)
#pragma unroll
        for (int ni = 0; ni < 4; ++ni)
          accf[mi][ni] = __builtin_amdgcn_mfma_f32_16x16x32_bf16(
              a[mi], b[ni], accf[mi][ni], 0, 0, 0);
    }
    __syncthreads();
  }

  const int rg = (lane >> 4) * 4;
  const int cl = lane & 15;
#pragma unroll
  for (int mi = 0; mi < 4; ++mi) {
#pragma unroll
    for (int r = 0; r < 4; ++r) {
      const int row = wm + mi * 16 + rg + r;
      const size_t t = (size_t)(m0 + row);
      const float4 hq = *(const float4*)(&hpost_sm[row][0]);
      const float4 h0 = *(const float4*)(&hres_sm[row][0]);
      const float4 h1 = *(const float4*)(&hres_sm[row][4]);
      const float4 h2 = *(const float4*)(&hres_sm[row][8]);
      const float4 h3 = *(const float4*)(&hres_sm[row][12]);
      const float* xp = x + t * 4096 + n0 + wn + cl;
      float* op = out + t * 4096 + n0 + wn + cl;
#pragma unroll
      for (int ni = 0; ni < 4; ++ni) {
        const int c = ni * 16;
        float x0 = xp[c], x1 = xp[c + 1024], x2 = xp[c + 2048], x3 = xp[c + 3072];
        float y = accf[mi][ni][r];
        op[c]        = x0 * h0.x + x1 * h0.y + x2 * h0.z + x3 * h0.w + hq.x * y;
        op[c + 1024] = x0 * h1.x + x1 * h1.y + x2 * h1.z + x3 * h1.w + hq.y * y;
        op[c + 2048] = x0 * h2.x + x1 * h2.y + x2 * h2.z + x3 * h2.w + hq.z * y;
        op[c + 3072] = x0 * h3.x + x1 * h3.y + x2 * h3.z + x3 * h3.w + hq.w * y;
      }
    }
  }
}

extern "C" void kernel_launch(void* const* d_in, const int* in_sizes, int n_in,
                              void* d_out, int out_size, void* d_ws, size_t ws_size,
                              hipStream_t stream) {
  const float* x     = (const float*)d_in[0];
  const float* rms_w = (const float*)d_in[1];
  const float* Wpre  = (const float*)d_in[2];
  const float* Wpost = (const float*)d_in[3];
  const float* Wres  = (const float*)d_in[4];
  const float* bpre  = (const float*)d_in[5];
  const float* bpost = (const float*)d_in[6];
  const float* bres  = (const float*)d_in[7];
  const float* apre  = (const float*)d_in[8];
  const float* apost = (const float*)d_in[9];
  const float* ares  = (const float*)d_in[10];
  const float* Wsub  = (const float*)d_in[11];
  float* out = (float*)d_out;

  char* ws = (char*)d_ws;
  float* gates           = (float*)ws;                         // 640 KB
  unsigned short* Wb     = (unsigned short*)(ws + (1 << 20));  // 2 MB
  unsigned short* Wg     = (unsigned short*)(ws + (3 << 20));  // 256 KB
  unsigned short* xlayer = (unsigned short*)(ws + (4 << 20));  // 16 MB

  prep_kernel<<<2304, 256, 0, stream>>>(Wpre, Wpost, Wres, rms_w, Wsub, Wg, Wb);
  gates_kernel<<<1024, 512, 0, stream>>>(x, Wg, bpre, bpost, bres,
                                         apre, apost, ares, gates, xlayer);
  gemm_epi<<<dim3(8, 64), 256, 0, stream>>>(xlayer, Wb, x, gates, out);
}